// Round 1
// baseline (439.122 us; speedup 1.0000x reference)
//
#include <hip/hip_runtime.h>

#define BB 512
#define SS 1024
#define TT 48

// broadcast lane i's value of v to all lanes (compile-time i -> v_readlane_b32)
__device__ __forceinline__ float lanebc(float v, int i) {
    return __int_as_float(__builtin_amdgcn_readlane(__float_as_int(v), i));
}

__device__ __forceinline__ float wave_max(float v) {
#pragma unroll
    for (int off = 32; off >= 1; off >>= 1)
        v = fmaxf(v, __shfl_xor(v, off, 64));
    return v;
}
__device__ __forceinline__ float wave_sum(float v) {
#pragma unroll
    for (int off = 32; off >= 1; off >>= 1)
        v += __shfl_xor(v, off, 64);
    return v;
}
__device__ __forceinline__ int wave_sum_i(int v) {
#pragma unroll
    for (int off = 32; off >= 1; off >>= 1)
        v += __shfl_xor(v, off, 64);
    return v;
}

// One block (1 wave, 64 lanes) per batch element.
// Lane j owns CRF state j (j < 48); lanes 48..63 carry zeros.
// Forward algorithm in scaled-linear domain:
//   p'_j = (sum_i p_i * expT[i][j]) * exp(emit[s][j]),  score = logscale + log p
// renormalize by wave-max every 4 steps (worst-case 4-step log growth ~42 < 88).
__global__ __launch_bounds__(64)
void crf_batch_kernel(const float* __restrict__ emissions,
                      const int* __restrict__ tags,
                      const int* __restrict__ mask,
                      const float* __restrict__ start_tr,
                      const float* __restrict__ end_tr,
                      const float* __restrict__ trans,
                      float* __restrict__ per_b) {
    const int b = blockIdx.x;
    const int lane = threadIdx.x;
    const bool act = lane < TT;

    const float* em_b = emissions + (size_t)b * SS * TT;
    const int* tg_b = tags + (size_t)b * SS;
    const int* mk_b = mask + (size_t)b * SS;

    // ---- length = sum(mask[b,:])  (prefix mask) ----
    int lc = 0;
    for (int s = lane; s < SS; s += 64) lc += (mk_b[s] != 0);
    const int len = wave_sum_i(lc);  // wave-uniform, 1 <= len <= SS

    // ---- lane j holds column j of exp(transitions): col[i] = exp(T[i][j]) ----
    float col[TT];
#pragma unroll
    for (int i = 0; i < TT; ++i)
        col[i] = act ? __expf(trans[i * TT + lane]) : 0.0f;

    // ---- init: score0 = start + emit[0]; p = exp(score0 - max), logscale = max
    float sc0 = act ? (start_tr[lane] + em_b[lane]) : -3.0e38f;
    float m0 = wave_max(sc0);
    float p = act ? __expf(sc0 - m0) : 0.0f;
    float logscale = m0;

    const int nsteps = len - 1;  // update steps s = 1 .. len-1

    // software-pipelined emission prefetch, 8 steps per chunk
    float eb[8];
#pragma unroll
    for (int k = 0; k < 8; ++k) {
        int ss = 1 + k; if (ss > SS - 1) ss = SS - 1;   // clamp: safe, unused if OOB
        eb[k] = act ? em_b[ss * TT + lane] : 0.0f;
    }

    int step = 0;
    while (step < nsteps) {
        // issue next chunk's loads before computing current chunk
        float en[8];
#pragma unroll
        for (int k = 0; k < 8; ++k) {
            int ss = 1 + step + 8 + k; if (ss > SS - 1) ss = SS - 1;
            en[k] = act ? em_b[ss * TT + lane] : 0.0f;
        }
        int cnt = nsteps - step; if (cnt > 8) cnt = 8;  // wave-uniform

#pragma unroll
        for (int k = 0; k < 8; ++k) {
            if (k < cnt) {
                // 48x48 matvec via readlane broadcast, 4 independent FMA chains
                float a0 = 0.f, a1 = 0.f, a2 = 0.f, a3 = 0.f;
#pragma unroll
                for (int i = 0; i < TT; i += 4) {
                    a0 = fmaf(lanebc(p, i    ), col[i    ], a0);
                    a1 = fmaf(lanebc(p, i + 1), col[i + 1], a1);
                    a2 = fmaf(lanebc(p, i + 2), col[i + 2], a2);
                    a3 = fmaf(lanebc(p, i + 3), col[i + 3], a3);
                }
                p = ((a0 + a1) + (a2 + a3)) * __expf(eb[k]);
                if ((k & 3) == 3) {  // renormalize every 4 steps
                    float m = wave_max(p);
                    logscale += __logf(m);
                    p *= __builtin_amdgcn_rcpf(m);
                }
            }
        }
#pragma unroll
        for (int k = 0; k < 8; ++k) eb[k] = en[k];
        step += 8;
    }

    // ---- log partition: logscale + log(sum_j p_j * exp(end_j)) ----
    float pe = p * (act ? __expf(end_tr[lane]) : 1.0f);  // p==0 on inactive lanes
    float denom = logscale + __logf(wave_sum(pe));

    // ---- numerator: path score of the gold tags ----
    float ns = 0.f;
    for (int s = lane; s < SS; s += 64) {
        if (s >= 1 && s < len) {
            int tp = tg_b[s - 1], tc = tg_b[s];
            ns += trans[tp * TT + tc] + em_b[s * TT + tc];
        }
    }
    float num = wave_sum(ns);
    int tag0 = tg_b[0];
    int tagl = tg_b[len - 1];
    num += start_tr[tag0] + em_b[tag0] + end_tr[tagl];

    if (lane == 0) per_b[b] = denom - num;
}

__global__ __launch_bounds__(64)
void reduce_mean_kernel(const float* __restrict__ per_b, float* __restrict__ out) {
    int lane = threadIdx.x;
    float s = 0.f;
    for (int i = lane; i < BB; i += 64) s += per_b[i];
    s = wave_sum(s);
    if (lane == 0) out[0] = s * (1.0f / (float)BB);
}

extern "C" void kernel_launch(void* const* d_in, const int* in_sizes, int n_in,
                              void* d_out, int out_size, void* d_ws, size_t ws_size,
                              hipStream_t stream) {
    const float* emissions = (const float*)d_in[0];
    const int*   tags      = (const int*)d_in[1];
    const int*   mask      = (const int*)d_in[2];
    const float* start_tr  = (const float*)d_in[3];
    const float* end_tr    = (const float*)d_in[4];
    const float* trans     = (const float*)d_in[5];
    float* per_b = (float*)d_ws;  // 512 floats of scratch

    crf_batch_kernel<<<BB, 64, 0, stream>>>(emissions, tags, mask,
                                            start_tr, end_tr, trans, per_b);
    reduce_mean_kernel<<<1, 64, 0, stream>>>(per_b, (float*)d_out);
}

// Round 2
// 422.209 us; speedup vs baseline: 1.0401x; 1.0401x over previous
//
#include <hip/hip_runtime.h>

#define BB 512
#define SS 1024
#define TT 48
#define GG 16          // batches per wave in the MFMA kernel
#define PF 8           // emission prefetch depth (ring slots)

typedef __attribute__((ext_vector_type(8))) short short8;
typedef __attribute__((ext_vector_type(4))) float float4v;

// ---------- helpers ----------
__device__ __forceinline__ unsigned short f2bf(float x) {  // RNE float->bf16 (finite, +ve)
    unsigned u = __float_as_uint(x);
    u += 0x7FFFu + ((u >> 16) & 1u);
    return (unsigned short)(u >> 16);
}
__device__ __forceinline__ float wave_sum(float v) {
#pragma unroll
    for (int off = 32; off >= 1; off >>= 1) v += __shfl_xor(v, off, 64);
    return v;
}
__device__ __forceinline__ int wave_sum_i(int v) {
#pragma unroll
    for (int off = 32; off >= 1; off >>= 1) v += __shfl_xor(v, off, 64);
    return v;
}

// ---------- prep: expE (bf16) + lengths + numerator, one block per batch ----------
template<bool PRE>
__global__ __launch_bounds__(256)
void crf_prep(const float* __restrict__ em, const int* __restrict__ tags,
              const int* __restrict__ mask, const float* __restrict__ start_tr,
              const float* __restrict__ end_tr, const float* __restrict__ trans,
              float* __restrict__ numer, int* __restrict__ lenArr,
              unsigned short* __restrict__ expE) {
    const int b = blockIdx.x, tid = threadIdx.x;
    const float* emb = em + (size_t)b * SS * TT;
    const int* tg = tags + (size_t)b * SS;
    const int* mk = mask + (size_t)b * SS;

    if (PRE) {  // exp(emissions) -> bf16
        unsigned short* outb = expE + (size_t)b * SS * TT;
        const float4* src = (const float4*)emb;
        for (int i = tid; i < SS * TT / 4; i += 256) {
            float4 v = src[i];
            unsigned u0 = (unsigned)f2bf(__expf(v.x)) | ((unsigned)f2bf(__expf(v.y)) << 16);
            unsigned u1 = (unsigned)f2bf(__expf(v.z)) | ((unsigned)f2bf(__expf(v.w)) << 16);
            uint2 o; o.x = u0; o.y = u1;
            ((uint2*)outb)[i] = o;
        }
    }
    // lengths + gold-path score
    int cnt = 0; float ns = 0.f;
    for (int s = tid; s < SS; s += 256) {
        int m = mk[s];
        cnt += (m != 0);
        if (s >= 1 && m) {
            int tp = tg[s - 1], tc = tg[s];
            ns += trans[tp * TT + tc] + emb[s * TT + tc];
        }
    }
    float wsum = wave_sum(ns);
    int wcnt = wave_sum_i(cnt);
    __shared__ float sf[4]; __shared__ int si[4];
    if ((tid & 63) == 0) { sf[tid >> 6] = wsum; si[tid >> 6] = wcnt; }
    __syncthreads();
    if (tid == 0) {
        float tot = sf[0] + sf[1] + sf[2] + sf[3];
        int L = si[0] + si[1] + si[2] + si[3];
        int t0 = tg[0];
        tot += start_tr[t0] + emb[t0] + end_tr[tg[L - 1]];
        numer[b] = tot;
        lenArr[b] = L;
    }
}

// ---------- main: 1 wave = 16 batches, MFMA recurrence, zero cross-lane chaining ----------
// state s lives at: lane quad q=(s/4)%4, C-reg r=s%4, tile mt=s/16 (C layout: col=lane&15=batch)
// k-slot:  kappa(s) = 32*(s/16) + 8*((s/4)%4) + (s%4)  -> B layout (n=lane&15, k=quad*8+j)
// => C-reg pair (2h,2h+1) of tile g packs (1 v_perm) directly into B-frag[g] reg h. No LDS.
template<bool PRE>
__global__ __launch_bounds__(64)
void crf_fwd(const float* __restrict__ em, const float* __restrict__ start_tr,
             const float* __restrict__ end_tr, const float* __restrict__ trans,
             const unsigned short* __restrict__ expE, const int* __restrict__ lenArr,
             float* __restrict__ denomArr) {
    const int lane = threadIdx.x & 63;
    const int n = lane & 15, q = lane >> 4;
    const int bb = blockIdx.x * GG + n;

    // A[m=s_out][k=kappa(s_in)] = exp(trans[s_out][s_in])   (reference: T[next][prev])
    short8 afr[3][3];
#pragma unroll
    for (int mt = 0; mt < 3; ++mt) {
#pragma unroll
        for (int kt = 0; kt < 3; ++kt) {
            short8 a;
#pragma unroll
            for (int i = 0; i < 8; ++i) {
                if (i < 4) {
                    int si_ = kt * 16 + q * 4 + i;   // s_in
                    int so_ = mt * 16 + n;           // s_out
                    a[i] = (short)f2bf(__expf(trans[so_ * TT + si_]));
                } else a[i] = 0;
            }
            afr[mt][kt] = a;
        }
    }

    const unsigned short* erow = expE + (size_t)bb * SS * TT;
    const float* frow = em + (size_t)bb * SS * TT;

    float eEnd[3][4], p[3][4];
#pragma unroll
    for (int mt = 0; mt < 3; ++mt) {
        int sb = mt * 16 + q * 4;
        float e0[4];
        if (PRE) {
            uint2 e = *(const uint2*)(erow + sb);
            e0[0] = __uint_as_float(e.x << 16); e0[1] = __uint_as_float(e.x & 0xFFFF0000u);
            e0[2] = __uint_as_float(e.y << 16); e0[3] = __uint_as_float(e.y & 0xFFFF0000u);
        } else {
            float4 r4 = *(const float4*)(frow + sb);
            e0[0] = __expf(r4.x); e0[1] = __expf(r4.y); e0[2] = __expf(r4.z); e0[3] = __expf(r4.w);
        }
#pragma unroll
        for (int r = 0; r < 4; ++r) {
            int s = sb + r;
            eEnd[mt][r] = __expf(end_tr[s]);
            p[mt][r] = __expf(start_tr[s]) * e0[r];   // score0 = start + emit0, linear domain
        }
    }

    const int len = lenArr[bb];
    int Lmax = len;
#pragma unroll
    for (int off = 1; off < 64; off <<= 1) {
        int o = __shfl_xor(Lmax, off, 64);
        Lmax = Lmax > o ? Lmax : o;
    }

    float logscale = 0.f, denomv = 0.f;
    auto snap = [&](int tcur) {   // denom_n = logscale + log(sum_s p*exp(end))
        float pe = 0.f;
#pragma unroll
        for (int mt = 0; mt < 3; ++mt)
#pragma unroll
            for (int r = 0; r < 4; ++r) pe = fmaf(p[mt][r], eEnd[mt][r], pe);
        pe += __shfl_xor(pe, 16, 64);
        pe += __shfl_xor(pe, 32, 64);
        float d = logscale + __logf(pe);
        denomv = (len == tcur + 1) ? d : denomv;
    };
    if (__ballot(len == 1)) snap(0);

    uint2 ringE[PF][3];
    float4 ringF[PF][3];
    auto prefetch = [&](int trow, int slot) {
        int row = trow < SS ? trow : SS - 1;
        if (PRE) {
#pragma unroll
            for (int mt = 0; mt < 3; ++mt)
                ringE[slot][mt] = *(const uint2*)(erow + row * TT + mt * 16 + q * 4);
        } else {
#pragma unroll
            for (int mt = 0; mt < 3; ++mt)
                ringF[slot][mt] = *(const float4*)(frow + row * TT + mt * 16 + q * 4);
        }
    };
#pragma unroll
    for (int tp = 1; tp <= PF; ++tp) prefetch(tp, tp & (PF - 1));

    for (int tb = 1; tb < Lmax; tb += 8) {
#pragma unroll
        for (int u = 0; u < 8; ++u) {
            const int slot = (1 + u) & (PF - 1);   // tb == 1 (mod 8)
            const int t = tb + u;
            if (t < Lmax) {
                // pack p (f32) -> B frags: RNE-ish via +0x8000 then byte-perm hi16s
                short8 bfr[3];
#pragma unroll
                for (int kt = 0; kt < 3; ++kt) {
                    unsigned pk0 = __builtin_amdgcn_perm(
                        __float_as_uint(p[kt][1]) + 0x8000u,
                        __float_as_uint(p[kt][0]) + 0x8000u, 0x07060302u);
                    unsigned pk1 = __builtin_amdgcn_perm(
                        __float_as_uint(p[kt][3]) + 0x8000u,
                        __float_as_uint(p[kt][2]) + 0x8000u, 0x07060302u);
                    union { short8 v; unsigned u4[4]; } bu;
                    bu.u4[0] = pk0; bu.u4[1] = pk1; bu.u4[2] = 0; bu.u4[3] = 0;
                    bfr[kt] = bu.v;
                }
#pragma unroll
                for (int mt = 0; mt < 3; ++mt) {
                    float4v acc = {0.f, 0.f, 0.f, 0.f};
                    acc = __builtin_amdgcn_mfma_f32_16x16x32_bf16(afr[mt][0], bfr[0], acc, 0, 0, 0);
                    acc = __builtin_amdgcn_mfma_f32_16x16x32_bf16(afr[mt][1], bfr[1], acc, 0, 0, 0);
                    acc = __builtin_amdgcn_mfma_f32_16x16x32_bf16(afr[mt][2], bfr[2], acc, 0, 0, 0);
                    float e0, e1, e2, e3;
                    if (PRE) {
                        uint2 e = ringE[slot][mt];
                        e0 = __uint_as_float(e.x << 16); e1 = __uint_as_float(e.x & 0xFFFF0000u);
                        e2 = __uint_as_float(e.y << 16); e3 = __uint_as_float(e.y & 0xFFFF0000u);
                    } else {
                        float4 r4 = ringF[slot][mt];
                        e0 = __expf(r4.x); e1 = __expf(r4.y); e2 = __expf(r4.z); e3 = __expf(r4.w);
                    }
                    p[mt][0] = acc[0] * e0; p[mt][1] = acc[1] * e1;
                    p[mt][2] = acc[2] * e2; p[mt][3] = acc[3] * e3;
                }
                prefetch(t + PF, slot);
                if (__ballot(len == t + 1)) snap(t);
                if (u == 7) {   // renorm every 8 steps (t = 8,16,...)
                    float m = p[0][0];
#pragma unroll
                    for (int mt = 0; mt < 3; ++mt)
#pragma unroll
                        for (int r = 0; r < 4; ++r) m = fmaxf(m, p[mt][r]);
                    m = fmaxf(m, __shfl_xor(m, 16, 64));
                    m = fmaxf(m, __shfl_xor(m, 32, 64));
                    logscale += __logf(m);
                    float rm = __builtin_amdgcn_rcpf(m);
#pragma unroll
                    for (int mt = 0; mt < 3; ++mt)
#pragma unroll
                        for (int r = 0; r < 4; ++r) p[mt][r] *= rm;
                }
            }
        }
    }
    if (lane < 16) denomArr[bb] = denomv;
}

__global__ __launch_bounds__(64)
void crf_reduce(const float* __restrict__ denom, const float* __restrict__ numer,
                float* __restrict__ out) {
    int lane = threadIdx.x;
    float s = 0.f;
    for (int i = lane; i < BB; i += 64) s += denom[i] - numer[i];
    s = wave_sum(s);
    if (lane == 0) out[0] = s * (1.0f / (float)BB);
}

extern "C" void kernel_launch(void* const* d_in, const int* in_sizes, int n_in,
                              void* d_out, int out_size, void* d_ws, size_t ws_size,
                              hipStream_t stream) {
    const float* emissions = (const float*)d_in[0];
    const int*   tags      = (const int*)d_in[1];
    const int*   mask      = (const int*)d_in[2];
    const float* start_tr  = (const float*)d_in[3];
    const float* end_tr    = (const float*)d_in[4];
    const float* trans     = (const float*)d_in[5];

    char* ws = (char*)d_ws;
    float* denom = (float*)ws;                       // 512 f32
    float* numer = (float*)(ws + 2048);              // 512 f32
    int*   lenA  = (int*)(ws + 4096);                // 512 i32
    unsigned short* expE = (unsigned short*)(ws + 8192);
    const size_t need = 8192 + (size_t)BB * SS * TT * 2;
    const bool pre = ws_size >= need;

    if (pre) {
        crf_prep<true><<<BB, 256, 0, stream>>>(emissions, tags, mask, start_tr,
                                               end_tr, trans, numer, lenA, expE);
        crf_fwd<true><<<BB / GG, 64, 0, stream>>>(emissions, start_tr, end_tr, trans,
                                                  expE, lenA, denom);
    } else {
        crf_prep<false><<<BB, 256, 0, stream>>>(emissions, tags, mask, start_tr,
                                                end_tr, trans, numer, lenA, expE);
        crf_fwd<false><<<BB / GG, 64, 0, stream>>>(emissions, start_tr, end_tr, trans,
                                                   expE, lenA, denom);
    }
    crf_reduce<<<1, 64, 0, stream>>>(denom, numer, (float*)d_out);
}

// Round 3
// 414.404 us; speedup vs baseline: 1.0596x; 1.0188x over previous
//
#include <hip/hip_runtime.h>

#define BB 512
#define SS 1024
#define TT 48
#define GG 16          // batches per wave (MFMA N)
#define PF 8           // prefetch depth (must divide unroll=8)

typedef __attribute__((ext_vector_type(8))) short short8;
typedef __attribute__((ext_vector_type(4))) float float4v;

// ---------- helpers ----------
__device__ __forceinline__ unsigned short f2bf(float x) {  // RNE f32->bf16
    unsigned u = __float_as_uint(x);
    u += 0x7FFFu + ((u >> 16) & 1u);
    return (unsigned short)(u >> 16);
}
// pack two f32 -> one uint holding (bf16(lo) | bf16(hi)<<16)
__device__ __forceinline__ unsigned pk2bf(float lo, float hi) {
#if __has_builtin(__builtin_amdgcn_cvt_pk_bf16_f32)
    typedef __bf16 bf16x2 __attribute__((ext_vector_type(2)));
    union { bf16x2 v; unsigned u; } cv;
    cv.v = __builtin_amdgcn_cvt_pk_bf16_f32(lo, hi);
    return cv.u;
#else
    return __builtin_amdgcn_perm(__float_as_uint(hi) + 0x8000u,
                                 __float_as_uint(lo) + 0x8000u, 0x07060302u);
#endif
}
__device__ __forceinline__ float wave_sum(float v) {
#pragma unroll
    for (int off = 32; off >= 1; off >>= 1) v += __shfl_xor(v, off, 64);
    return v;
}
__device__ __forceinline__ int wave_sum_i(int v) {
#pragma unroll
    for (int off = 32; off >= 1; off >>= 1) v += __shfl_xor(v, off, 64);
    return v;
}

// ---------- prep1: expE[b][t][s] = mask[b][t] ? exp(em[b][t][s]) : 0  (bf16) ----------
__global__ __launch_bounds__(256)
void crf_exp(const float* __restrict__ em, const int* __restrict__ mask,
             uint2* __restrict__ expE) {
    const int NF4 = BB * SS * TT / 4;          // 6.29M float4s
    int idx = blockIdx.x * 256 + threadIdx.x;
    const int stride = gridDim.x * 256;
    const float4* src = (const float4*)em;
    for (int f = idx; f < NF4; f += stride) {
        int bt = f / (TT / 4);                 // b*SS + t
        int m = mask[bt];
        float4 v = src[f];
        uint2 o;
        if (m) {
            o.x = (unsigned)f2bf(__expf(v.x)) | ((unsigned)f2bf(__expf(v.y)) << 16);
            o.y = (unsigned)f2bf(__expf(v.z)) | ((unsigned)f2bf(__expf(v.w)) << 16);
        } else { o.x = 0u; o.y = 0u; }
        expE[f] = o;
    }
}

// ---------- prep2: lengths + gold-path numerator, one block per batch ----------
__global__ __launch_bounds__(256)
void crf_numer(const float* __restrict__ em, const int* __restrict__ tags,
               const int* __restrict__ mask, const float* __restrict__ start_tr,
               const float* __restrict__ end_tr, const float* __restrict__ trans,
               float* __restrict__ numer, int* __restrict__ lenArr) {
    const int b = blockIdx.x, tid = threadIdx.x;
    const float* emb = em + (size_t)b * SS * TT;
    const int* tg = tags + (size_t)b * SS;
    const int* mk = mask + (size_t)b * SS;
    int cnt = 0; float ns = 0.f;
    for (int s = tid; s < SS; s += 256) {
        int m = mk[s];
        cnt += (m != 0);
        if (s >= 1 && m) {
            int tp = tg[s - 1], tc = tg[s];
            ns += trans[tp * TT + tc] + emb[s * TT + tc];
        }
    }
    float wsum = wave_sum(ns);
    int wcnt = wave_sum_i(cnt);
    __shared__ float sf[4]; __shared__ int si[4];
    if ((tid & 63) == 0) { sf[tid >> 6] = wsum; si[tid >> 6] = wcnt; }
    __syncthreads();
    if (tid == 0) {
        float tot = sf[0] + sf[1] + sf[2] + sf[3];
        int L = si[0] + si[1] + si[2] + si[3];
        int t0 = tg[0];
        tot += start_tr[t0] + emb[t0] + end_tr[tg[L - 1]];
        numer[b] = tot;
        lenArr[b] = L;
    }
}

// ---------- main recurrence: 1 wave = 16 batches, 6 MFMA/step, branchless ----------
// State s = 16a + 4q + r lives in C tile a, quad q, reg r (col = lane&15 = batch).
// B k-slot map: states 0..31 -> frag0 (j = 4a + r in quad q); states 32..47 -> frag1 j=r.
// C reg pairs map register-for-register into B frags via one pack each: no cross-lane.
template<bool PRE>
__global__ __launch_bounds__(64)
void crf_fwd(const float* __restrict__ em, const uint2* __restrict__ expE,
             const float* __restrict__ start_tr, const float* __restrict__ end_tr,
             const float* __restrict__ trans, const int* __restrict__ lenArr,
             float* __restrict__ denomArr) {
    const int lane = threadIdx.x & 63;
    const int n = lane & 15, q = lane >> 4;
    const int bb = blockIdx.x * GG + n;

    // A[m = s_out][k-slot(s_in)] = exp(trans[s_out][s_in])  (denominator uses T[next][prev])
    short8 afr[3][2];
#pragma unroll
    for (int mt = 0; mt < 3; ++mt) {
        const int so = mt * 16 + n;
#pragma unroll
        for (int kt = 0; kt < 2; ++kt) {
            short8 a;
#pragma unroll
            for (int i = 0; i < 8; ++i) {
                int si_;
                if (kt == 0) si_ = (i < 4) ? (q * 4 + i) : (16 + q * 4 + (i - 4));
                else         si_ = (i < 4) ? (32 + q * 4 + i) : -1;
                a[i] = (si_ >= 0) ? (short)f2bf(__expf(trans[so * TT + si_])) : (short)0;
            }
            afr[mt][kt] = a;
        }
    }

    const char* ebase;
    if (PRE) ebase = (const char*)expE + (size_t)bb * SS * (TT * 2) + (size_t)q * 8;
    else     ebase = (const char*)em   + (size_t)bb * SS * (TT * 4) + (size_t)q * 16;

    // init: p = exp(start) * e_row0 ; logscale = 0
    float eEnd[3][4], p[3][4];
#pragma unroll
    for (int mt = 0; mt < 3; ++mt) {
        float e0[4];
        if (PRE) {
            uint2 e = *(const uint2*)(ebase + mt * 32);
            e0[0] = __uint_as_float(e.x << 16); e0[1] = __uint_as_float(e.x & 0xFFFF0000u);
            e0[2] = __uint_as_float(e.y << 16); e0[3] = __uint_as_float(e.y & 0xFFFF0000u);
        } else {
            float4 r4 = *(const float4*)(ebase + mt * 64);
            e0[0] = __expf(r4.x); e0[1] = __expf(r4.y); e0[2] = __expf(r4.z); e0[3] = __expf(r4.w);
        }
#pragma unroll
        for (int r = 0; r < 4; ++r) {
            int s = mt * 16 + q * 4 + r;
            eEnd[mt][r] = __expf(end_tr[s]);
            p[mt][r] = __expf(start_tr[s]) * e0[r];
        }
    }

    const int len = lenArr[bb];
    int Lmax = len;
#pragma unroll
    for (int off = 1; off < 64; off <<= 1) {
        int o = __shfl_xor(Lmax, off, 64);
        Lmax = Lmax > o ? Lmax : o;
    }

    // capture registers (branchless latch)
    float pe0 = 0.f;
#pragma unroll
    for (int mt = 0; mt < 3; ++mt)
#pragma unroll
        for (int r = 0; r < 4; ++r) pe0 = fmaf(p[mt][r], eEnd[mt][r], pe0);
    float dcap = (len == 1) ? pe0 : 0.f;
    float lcap = 0.f;
    float logscale = 0.f;

    // prefetch ring
    uint2  ringE[PF][3];
    float4 ringF[PF][3];
#pragma unroll
    for (int tp = 1; tp <= PF; ++tp) {
        const int slot = tp & (PF - 1);
        if (PRE) {
#pragma unroll
            for (int mt = 0; mt < 3; ++mt)
                ringE[slot][mt] = *(const uint2*)(ebase + (size_t)tp * 96 + mt * 32);
        } else {
#pragma unroll
            for (int mt = 0; mt < 3; ++mt)
                ringF[slot][mt] = *(const float4*)(ebase + (size_t)tp * 192 + mt * 64);
        }
    }

    const float4v Z = {0.f, 0.f, 0.f, 0.f};

    for (int tb = 1; tb < Lmax; tb += 8) {
#pragma unroll
        for (int u = 0; u < 8; ++u) {
            const int t = tb + u;
            const int slot = (1 + u) & (PF - 1);

            // ---- pack p -> B frags (6 packs, register-for-register) ----
            union { short8 v; unsigned w[4]; } B0, B1;
            B0.w[0] = pk2bf(p[0][0], p[0][1]);
            B0.w[1] = pk2bf(p[0][2], p[0][3]);
            B0.w[2] = pk2bf(p[1][0], p[1][1]);
            B0.w[3] = pk2bf(p[1][2], p[1][3]);
            B1.w[0] = pk2bf(p[2][0], p[2][1]);
            B1.w[1] = pk2bf(p[2][2], p[2][3]);
            B1.w[2] = 0u; B1.w[3] = 0u;

            // ---- 6 MFMAs, 3 independent 2-deep chains ----
            float4v A0 = __builtin_amdgcn_mfma_f32_16x16x32_bf16(afr[0][0], B0.v, Z, 0, 0, 0);
            float4v A1 = __builtin_amdgcn_mfma_f32_16x16x32_bf16(afr[1][0], B0.v, Z, 0, 0, 0);
            float4v A2 = __builtin_amdgcn_mfma_f32_16x16x32_bf16(afr[2][0], B0.v, Z, 0, 0, 0);
            A0 = __builtin_amdgcn_mfma_f32_16x16x32_bf16(afr[0][1], B1.v, A0, 0, 0, 0);
            A1 = __builtin_amdgcn_mfma_f32_16x16x32_bf16(afr[1][1], B1.v, A1, 0, 0, 0);
            A2 = __builtin_amdgcn_mfma_f32_16x16x32_bf16(afr[2][1], B1.v, A2, 0, 0, 0);

            // ---- p = acc * e_t  (masked rows are 0 -> finished batches freeze to 0) ----
            if (PRE) {
                uint2 e0 = ringE[slot][0], e1 = ringE[slot][1], e2 = ringE[slot][2];
                p[0][0] = A0[0] * __uint_as_float(e0.x << 16);
                p[0][1] = A0[1] * __uint_as_float(e0.x & 0xFFFF0000u);
                p[0][2] = A0[2] * __uint_as_float(e0.y << 16);
                p[0][3] = A0[3] * __uint_as_float(e0.y & 0xFFFF0000u);
                p[1][0] = A1[0] * __uint_as_float(e1.x << 16);
                p[1][1] = A1[1] * __uint_as_float(e1.x & 0xFFFF0000u);
                p[1][2] = A1[2] * __uint_as_float(e1.y << 16);
                p[1][3] = A1[3] * __uint_as_float(e1.y & 0xFFFF0000u);
                p[2][0] = A2[0] * __uint_as_float(e2.x << 16);
                p[2][1] = A2[1] * __uint_as_float(e2.x & 0xFFFF0000u);
                p[2][2] = A2[2] * __uint_as_float(e2.y << 16);
                p[2][3] = A2[3] * __uint_as_float(e2.y & 0xFFFF0000u);
            } else {
                float4 r0 = ringF[slot][0], r1 = ringF[slot][1], r2 = ringF[slot][2];
                p[0][0] = A0[0] * __expf(r0.x); p[0][1] = A0[1] * __expf(r0.y);
                p[0][2] = A0[2] * __expf(r0.z); p[0][3] = A0[3] * __expf(r0.w);
                p[1][0] = A1[0] * __expf(r1.x); p[1][1] = A1[1] * __expf(r1.y);
                p[1][2] = A1[2] * __expf(r1.z); p[1][3] = A1[3] * __expf(r1.w);
                p[2][0] = A2[0] * __expf(r2.x); p[2][1] = A2[1] * __expf(r2.y);
                p[2][2] = A2[2] * __expf(r2.z); p[2][3] = A2[3] * __expf(r2.w);
            }

            // ---- branchless capture at t == len-1 ----
            float s0 = fmaf(p[0][0], eEnd[0][0], fmaf(p[0][1], eEnd[0][1],
                       fmaf(p[0][2], eEnd[0][2], p[0][3] * eEnd[0][3])));
            float s1 = fmaf(p[1][0], eEnd[1][0], fmaf(p[1][1], eEnd[1][1],
                       fmaf(p[1][2], eEnd[1][2], p[1][3] * eEnd[1][3])));
            float s2 = fmaf(p[2][0], eEnd[2][0], fmaf(p[2][1], eEnd[2][1],
                       fmaf(p[2][2], eEnd[2][2], p[2][3] * eEnd[2][3])));
            float pe = s0 + s1 + s2;
            bool cc = (len == t + 1);
            dcap = cc ? pe : dcap;
            lcap = cc ? logscale : lcap;

            // ---- prefetch row t+PF (scalar-clamped row, uniform base) ----
            {
                int row = t + PF; row = row < SS ? row : SS - 1;   // wave-uniform
                if (PRE) {
#pragma unroll
                    for (int mt = 0; mt < 3; ++mt)
                        ringE[slot][mt] = *(const uint2*)(ebase + (size_t)row * 96 + mt * 32);
                } else {
#pragma unroll
                    for (int mt = 0; mt < 3; ++mt)
                        ringF[slot][mt] = *(const float4*)(ebase + (size_t)row * 192 + mt * 64);
                }
            }

            // ---- renorm every 8 steps (fixed unroll position, no branch) ----
            if (u == 7) {
                float m = p[0][0];
#pragma unroll
                for (int mt = 0; mt < 3; ++mt)
#pragma unroll
                    for (int r = 0; r < 4; ++r) m = fmaxf(m, p[mt][r]);
                m = fmaxf(m, __shfl_xor(m, 16, 64));
                m = fmaxf(m, __shfl_xor(m, 32, 64));
                m = fmaxf(m, 1e-37f);
                logscale += __logf(m);
                float rm = __builtin_amdgcn_rcpf(m);
#pragma unroll
                for (int mt = 0; mt < 3; ++mt)
#pragma unroll
                    for (int r = 0; r < 4; ++r) p[mt][r] *= rm;
            }
        }
    }

    // reduce dcap across the 4 quads holding the same batch
    dcap += __shfl_xor(dcap, 16, 64);
    dcap += __shfl_xor(dcap, 32, 64);
    if (lane < 16) denomArr[bb] = lcap + __logf(dcap);
}

__global__ __launch_bounds__(64)
void crf_reduce(const float* __restrict__ denom, const float* __restrict__ numer,
                float* __restrict__ out) {
    int lane = threadIdx.x;
    float s = 0.f;
    for (int i = lane; i < BB; i += 64) s += denom[i] - numer[i];
    s = wave_sum(s);
    if (lane == 0) out[0] = s * (1.0f / (float)BB);
}

extern "C" void kernel_launch(void* const* d_in, const int* in_sizes, int n_in,
                              void* d_out, int out_size, void* d_ws, size_t ws_size,
                              hipStream_t stream) {
    const float* emissions = (const float*)d_in[0];
    const int*   tags      = (const int*)d_in[1];
    const int*   mask      = (const int*)d_in[2];
    const float* start_tr  = (const float*)d_in[3];
    const float* end_tr    = (const float*)d_in[4];
    const float* trans     = (const float*)d_in[5];

    char* ws = (char*)d_ws;
    float* denom = (float*)ws;               // 512 f32
    float* numer = (float*)(ws + 2048);      // 512 f32
    int*   lenA  = (int*)(ws + 4096);        // 512 i32
    uint2* expE  = (uint2*)(ws + 8192);      // bf16 exp(emissions), 50.33 MB
    const size_t need = 8192 + (size_t)BB * SS * TT * 2;
    const bool pre = ws_size >= need;

    crf_numer<<<BB, 256, 0, stream>>>(emissions, tags, mask, start_tr, end_tr,
                                      trans, numer, lenA);
    if (pre) {
        crf_exp<<<2048, 256, 0, stream>>>(emissions, mask, expE);
        crf_fwd<true><<<BB / GG, 64, 0, stream>>>(emissions, expE, start_tr, end_tr,
                                                  trans, lenA, denom);
    } else {
        crf_fwd<false><<<BB / GG, 64, 0, stream>>>(emissions, expE, start_tr, end_tr,
                                                   trans, lenA, denom);
    }
    crf_reduce<<<1, 64, 0, stream>>>(denom, numer, (float*)d_out);
}